// Round 10
// baseline (467.171 us; speedup 1.0000x reference)
//
#include <hip/hip_runtime.h>

#define BB 4
#define CC 128
#define HH 128
#define WW 128
#define HW (HH*WW)
#define CHW (CC*HW)
#define ND 81
#define CP 136      // c-stride (shorts) for fgs: 272 B rows -> 16B aligned, 2-way-free b128 reads
#define PP 40       // P tile u stride (shorts): 80 B rows -> pa b128 read 2-way

typedef short s8v __attribute__((ext_vector_type(8)));   // 8 bf16 MFMA A/B frag
typedef short s4v __attribute__((ext_vector_type(4)));
typedef float f4v __attribute__((ext_vector_type(4)));   // MFMA C/D frag

__device__ __forceinline__ short f2bf(float x){          // RNE float->bf16 bits
  unsigned u = __float_as_uint(x);
  unsigned r = (u + 0x7FFFu + ((u >> 16) & 1u)) >> 16;
  return (short)r;
}
__device__ __forceinline__ float bf2f(short s){
  return __uint_as_float(((unsigned)(unsigned short)s) << 16);
}

// ---------------------------------------------------------------------------
// coef: paired sign-case tables, interleaved so the 3 cases hit different
// banks and one b64 gather fetches both values:
//   coef[(d*3+case)*2 + 0] = g2 = ga^2,  [..+1] = gt = ga*vp*t
//   ga = vp (s>0), vp*wm (s<0), vp*ah (s==0)    [a_lo+a_hi=1, a_hi-a_lo=wm]
// mapped m = g2*s - gt exactly; den elem = g2*t*t.
// [500]=step_length, [501]=reg_weight
// ---------------------------------------------------------------------------
__global__ void coef_kernel(const float* lw, const float* sw, const float* mw,
                            const float* lsl, const float* fr, float* coef){
  int d = threadIdx.x;
  if (d < ND){
    float dy = (float)(d / 9) - 4.0f;
    float dx = (float)(d % 9) - 4.0f;
    float dist = sqrtf(dy*dy + dx*dx) * 2.0f;
    float t = 0.f, v = 0.f, m = 0.f;
    for (int k = 0; k < 10; k++){
      float bd = dist - (float)k;
      float val = (k == 9) ? fminf(fmaxf(bd + 1.0f, 0.f), 1.f)
                           : fmaxf(1.0f - fabsf(bd), 0.f);
      t += val * lw[k]; v += val * sw[k]; m += val * mw[k];
    }
    float wm = 1.f / (1.f + expf(-m));
    float ah = (1.f + wm) * 0.5f;
    float gp = v, gn = v * wm, gz = v * ah;   // ga per sign case
    float vt = v * t;
    coef[(d*3+0)*2+0] = gp * gp;  coef[(d*3+0)*2+1] = gp * vt;
    coef[(d*3+1)*2+0] = gn * gn;  coef[(d*3+1)*2+1] = gn * vt;
    coef[(d*3+2)*2+0] = gz * gz;  coef[(d*3+2)*2+1] = gz * vt;
  }
  if (threadIdx.x == 0){
    coef[500] = expf(lsl[0]);
    float f = fr[0];
    coef[501] = fmaxf(f*f, 1e-10f) / (float)(CC*CC);
  }
}

// ---------------------------------------------------------------------------
// one-time convert: ref fp32 [b][c][h][w] ->
//   refU bf16 [b][h][c][w]  (u-contiguous, feeds corr_t B-frags)
//   refT bf16 [b][h][w][c]  (c-contiguous, feeds corr B-frags)
// ---------------------------------------------------------------------------
__global__ __launch_bounds__(256)
void cvt_kernel(const float* ref, short* refT, short* refU){
  __shared__ short T[128*130];
  int r = blockIdx.x, bb = blockIdx.y;
  int tid = threadIdx.x;
  const float* src = ref + (size_t)bb*CHW + (size_t)r*WW;
  short* uout = refU + (size_t)(bb*HH + r) * CC * WW;
  short* tout = refT + (size_t)(bb*HH + r) * WW * CC;
  #pragma unroll
  for (int k = 0; k < 16; k++){
    int q = tid + (k << 8);                 // 4096 float4 chunks
    int c = q >> 5, u0 = (q & 31) * 4;
    float4 v = *(const float4*)(src + (size_t)c*HW + u0);
    short h0 = f2bf(v.x), h1 = f2bf(v.y), h2 = f2bf(v.z), h3 = f2bf(v.w);
    s4v pk = {h0, h1, h2, h3};
    *(s4v*)&uout[(size_t)c*WW + u0] = pk;
    T[c*130 + u0 + 0] = h0; T[c*130 + u0 + 1] = h1;
    T[c*130 + u0 + 2] = h2; T[c*130 + u0 + 3] = h3;
  }
  __syncthreads();
  #pragma unroll
  for (int k = 0; k < 16; k++){
    int o = tid + (k << 8);
    int u = o >> 5, c0 = (o & 31) * 4;
    s4v pk = {T[(c0+0)*130 + u], T[(c0+1)*130 + u],
              T[(c0+2)*130 + u], T[(c0+3)*130 + u]};
    *(s4v*)&tout[(size_t)u*CC + c0] = pk;
  }
}

// ---------------------------------------------------------------------------
// kF round 10: BARRIER-FREE main loops. The uc/cu LDS staging (and its 48
// barriers + vmcnt(0) drains per block) is deleted; MFMA B-frags are b128
// loads straight from refT/refU (both layouts make each frag 16 contiguous
// bytes, L2-served, XCD-swizzle keeps the slice ~4MB = L2-sized). Each wave
// now loops over its OWN 9 valid rows (dy=0..8) -- no wasted iterations, no
// inter-wave lockstep; TLP hides L2 latency. LDS keeps only: Pm (wave-local
// handoff, lgkmcnt-only), fgs, coef table, reductions -> 25.3 KB, 4 barriers
// per launch. Numerics and accumulation order identical to R7.
// ---------------------------------------------------------------------------
#define L_PM   0        // 5120
#define L_FGS  5120     // 17408
#define L_CF   22528    // 512 floats = 2048
#define L_DEN  24576
#define L_NUM  24832
#define L_SA   25088
#define L_SZ   25344

template<int PRE>
__global__ __launch_bounds__(256, 4)
void kF(const float* f_in, const float* ref, const short* refT, const short* refU,
        const float* coef, float* f_out){
  __shared__ char smem[L_SZ];
  short* Pm  = (short*)(smem + L_PM);    // [4 wv][16 x][PP u] (wave-local)
  short* fgs = (short*)(smem + L_FGS);   // [64 px][CP c]  (fgrad)
  float* s_cf = (float*)(smem + L_CF);   // paired g2/gt table + step/rw
  float* den = (float*)(smem + L_DEN);
  float* num = (float*)(smem + L_NUM);
  float* sa  = (float*)(smem + L_SA);

  int tid = threadIdx.x;
  int lane = tid & 63, wv = tid >> 6;
  int quad = lane >> 4, col = lane & 15;

  // XCD-chunked bijective swizzle (1024 blocks, 8 XCDs)
  int hwid = blockIdx.x + (blockIdx.y << 3) + (blockIdx.z << 8);
  int virt = ((hwid & 7) << 7) + (hwid >> 3);
  int bb = virt >> 8, y0 = ((virt >> 3) & 31) * 4, x0 = (virt & 7) * 16;

  int ub = x0 - 8;
  bool interior = (ub >= 0) && (ub + 32 <= WW);

  const float* fimg = f_in + (size_t)bb * CHW;
  const float* rimg = ref  + (size_t)bb * CHW;
  const short* tb  = refT + (size_t)bb * HH * WW * CC;
  const short* ubp = refU + (size_t)bb * HH * CC * WW;

  for (int e = tid; e < 512; e += 256) s_cf[e] = coef[e];

  // ---- A-frags (f at row y0+wv, hi/lo split) straight from global ----
  int fy = y0 + wv;
  s8v a_hi[4], a_lo[4];
  #pragma unroll
  for (int kc = 0; kc < 4; kc++){
    short th[8], tl[8];
    #pragma unroll
    for (int j = 0; j < 8; j++){
      int c = kc*32 + quad*8 + j;
      float v = fimg[(size_t)c * HW + fy * WW + x0 + col];
      short h = f2bf(v);
      th[j] = h; tl[j] = f2bf(v - bf2f(h));
    }
    a_hi[kc] = *(const s8v*)th;
    a_lo[kc] = *(const s8v*)tl;
  }

  __syncthreads();            // s_cf visible to all waves

  float rw = s_cf[501];

  f4v D[8];
  #pragma unroll
  for (int i = 0; i < 8; i++) D[i] = (f4v)0.f;

  // sign FIFO: 9 x 16-bit packs in 3 u64 (push A, pop B, same order)
  unsigned long long f0 = 0ull, f1 = 0ull, f2 = 0ull;

  // =================== phase A: corr1 -> P -> corr_t (barrier-free) =========
  for (int dy = 0; dy <= 8; ++dy){
    int r = fy - 4 + dy;
    unsigned pack = 0u;
    if (r >= 0 && r < HH){
      const short* trow = tb  + (size_t)r * WW * CC;
      const short* urow = ubp + (size_t)r * CC * WW;
      // corr1: C[x,u] = sum_c (f_hi+f_lo)[x,c] * ref[c,u]
      f4v C0 = (f4v)0.f, C1 = (f4v)0.f;
      #pragma unroll
      for (int kc = 0; kc < 4; kc++){
        s8v b0, b1;
        if constexpr (PRE){
          if (interior){
            b0 = *(const s8v*)(trow + (ub +      col)*CC + kc*32 + quad*8);
            b1 = *(const s8v*)(trow + (ub + 16 + col)*CC + kc*32 + quad*8);
          } else {
            int ua0 = ub + col, ua1 = ub + 16 + col;
            b0 = (ua0 >= 0 && ua0 < WW)
                 ? *(const s8v*)(trow + ua0*CC + kc*32 + quad*8) : (s8v)(short)0;
            b1 = (ua1 >= 0 && ua1 < WW)
                 ? *(const s8v*)(trow + ua1*CC + kc*32 + quad*8) : (s8v)(short)0;
          }
        } else {
          short t0[8], t1[8];
          int ua0 = ub + col, ua1 = ub + 16 + col;
          #pragma unroll
          for (int j = 0; j < 8; j++){
            int c = kc*32 + quad*8 + j;
            t0[j] = (ua0 >= 0 && ua0 < WW) ? f2bf(rimg[(size_t)c*HW + r*WW + ua0]) : (short)0;
            t1[j] = (ua1 >= 0 && ua1 < WW) ? f2bf(rimg[(size_t)c*HW + r*WW + ua1]) : (short)0;
          }
          b0 = *(const s8v*)t0; b1 = *(const s8v*)t1;
        }
        C0 = __builtin_amdgcn_mfma_f32_16x16x32_bf16(a_hi[kc], b0, C0, 0,0,0);
        C0 = __builtin_amdgcn_mfma_f32_16x16x32_bf16(a_lo[kc], b0, C0, 0,0,0);
        C1 = __builtin_amdgcn_mfma_f32_16x16x32_bf16(a_hi[kc], b1, C1, 0,0,0);
        C1 = __builtin_amdgcn_mfma_f32_16x16x32_bf16(a_lo[kc], b1, C1, 0,0,0);
      }
      // scores -> sign pack (regs) + mapped -> P[x,u]
      #pragma unroll
      for (int nt = 0; nt < 2; nt++){
        f4v Cv = nt ? C1 : C0;
        #pragma unroll
        for (int reg = 0; reg < 4; reg++){
          int x  = quad*4 + reg;            // C/D row = (lane>>4)*4 + reg
          int up = nt*16 + col;             // C/D col = lane&15 (+tile)
          int dxm = up - x - 4;
          float m = 0.f;
          if ((unsigned)dxm <= 8u){
            float s = Cv[reg];
            int d = dy*9 + dxm;
            unsigned pos = (s > 0.f) ? 1u : 0u;
            unsigned neg = (s < 0.f) ? 1u : 0u;
            int cse = pos ? 0 : (neg ? 1 : 2);
            float2 gg = *(const float2*)&s_cf[(d*3 + cse)*2];
            m = fmaf(gg.x, s, -gg.y);
            pack |= (pos | (neg << 1)) << ((nt*4 + reg) * 2);
          }
          Pm[(wv*16 + x)*PP + up] = f2bf(m);
        }
      }
      // wave-local LDS handoff (keep global loads in flight)
      asm volatile("s_waitcnt lgkmcnt(0)" ::: "memory");
      __builtin_amdgcn_sched_barrier(0);
      // corr_t: D[x,c] += sum_u P[x,u] * ref[u,c]
      s8v pa = *(const s8v*)&Pm[(wv*16 + col)*PP + quad*8];
      #pragma unroll
      for (int ct = 0; ct < 8; ct++){
        s8v bc;
        if constexpr (PRE){
          if (interior){
            bc = *(const s8v*)(urow + (size_t)(ct*16 + col)*WW + ub + quad*8);
          } else {
            int ua = ub + quad*8;
            bc = (ua >= 0 && ua + 8 <= WW)
                 ? *(const s8v*)(urow + (size_t)(ct*16 + col)*WW + ua) : (s8v)(short)0;
          }
        } else {
          short t0[8];
          int c = ct*16 + col;
          #pragma unroll
          for (int j = 0; j < 8; j++){
            int ua = ub + quad*8 + j;
            t0[j] = (ua >= 0 && ua < WW) ? f2bf(rimg[(size_t)c*HW + r*WW + ua]) : (short)0;
          }
          bc = *(const s8v*)t0;
        }
        D[ct] = __builtin_amdgcn_mfma_f32_16x16x32_bf16(pa, bc, D[ct], 0,0,0);
      }
    }
    // FIFO push (always, so A/B stay aligned)
    f0 = (f0 >> 16) | (f1 << 48);
    f1 = (f1 >> 16) | (f2 << 48);
    f2 = (f2 >> 16) | ((unsigned long long)pack << 48);
  }

  // ---- epilogue-1: fgs = bf16(D + rw*f), then num ----
  #pragma unroll
  for (int ct = 0; ct < 8; ct++){
    #pragma unroll
    for (int reg = 0; reg < 4; reg++){
      int x = quad*4 + reg, c = ct*16 + col;
      float fv = fimg[(size_t)c * HW + fy * WW + x0 + x];
      fgs[(wv*16 + x)*CP + c] = f2bf(D[ct][reg] + rw * fv);
    }
  }
  __syncthreads();
  if (tid < 64){
    float s = 0.f;
    #pragma unroll
    for (int kc = 0; kc < 16; kc++){
      s8v v = *(const s8v*)&fgs[tid*CP + kc*8];
      #pragma unroll
      for (int j = 0; j < 8; j++){ float f = bf2f(v[j]); s += f*f; }
    }
    num[tid] = s;
  }

  // ============== phase B: corr(fgrad) -> den (barrier-free) ===============
  s8v ga_[4];
  #pragma unroll
  for (int kc = 0; kc < 4; kc++)
    ga_[kc] = *(const s8v*)&fgs[(wv*16 + col)*CP + kc*32 + quad*8];

  float dacc[4] = {0.f, 0.f, 0.f, 0.f};    // per-thread den partials (by reg)

  for (int dy = 0; dy <= 8; ++dy){
    int r = fy - 4 + dy;
    // FIFO pop (mirrors phase-A push order)
    unsigned pack = (unsigned)(f0 >> 48) & 0xFFFFu;
    f0 = (f0 >> 16) | (f1 << 48);
    f1 = (f1 >> 16) | (f2 << 48);
    f2 >>= 16;
    if (r >= 0 && r < HH){
      const short* trow = tb + (size_t)r * WW * CC;
      f4v C0 = (f4v)0.f, C1 = (f4v)0.f;
      #pragma unroll
      for (int kc = 0; kc < 4; kc++){
        s8v b0, b1;
        if constexpr (PRE){
          if (interior){
            b0 = *(const s8v*)(trow + (ub +      col)*CC + kc*32 + quad*8);
            b1 = *(const s8v*)(trow + (ub + 16 + col)*CC + kc*32 + quad*8);
          } else {
            int ua0 = ub + col, ua1 = ub + 16 + col;
            b0 = (ua0 >= 0 && ua0 < WW)
                 ? *(const s8v*)(trow + ua0*CC + kc*32 + quad*8) : (s8v)(short)0;
            b1 = (ua1 >= 0 && ua1 < WW)
                 ? *(const s8v*)(trow + ua1*CC + kc*32 + quad*8) : (s8v)(short)0;
          }
        } else {
          short t0[8], t1[8];
          int ua0 = ub + col, ua1 = ub + 16 + col;
          #pragma unroll
          for (int j = 0; j < 8; j++){
            int c = kc*32 + quad*8 + j;
            t0[j] = (ua0 >= 0 && ua0 < WW) ? f2bf(rimg[(size_t)c*HW + r*WW + ua0]) : (short)0;
            t1[j] = (ua1 >= 0 && ua1 < WW) ? f2bf(rimg[(size_t)c*HW + r*WW + ua1]) : (short)0;
          }
          b0 = *(const s8v*)t0; b1 = *(const s8v*)t1;
        }
        C0 = __builtin_amdgcn_mfma_f32_16x16x32_bf16(ga_[kc], b0, C0, 0,0,0);
        C1 = __builtin_amdgcn_mfma_f32_16x16x32_bf16(ga_[kc], b1, C1, 0,0,0);
      }
      #pragma unroll
      for (int nt = 0; nt < 2; nt++){
        f4v Cv = nt ? C1 : C0;
        #pragma unroll
        for (int reg = 0; reg < 4; reg++){
          int x  = quad*4 + reg;
          int up = nt*16 + col;
          int dxm = up - x - 4;
          if ((unsigned)dxm <= 8u){
            int d = dy*9 + dxm;
            unsigned b2 = pack >> ((nt*4 + reg) * 2);
            int cse = (b2 & 1u) ? 0 : ((b2 & 2u) ? 1 : 2);
            float g2 = s_cf[(d*3 + cse)*2];
            float t  = Cv[reg];
            dacc[reg] = fmaf(g2 * t, t, dacc[reg]);
          }
        }
      }
    }
  }

  // den: reduce partials across the 16 col-lanes of each quad (no atomics)
  #pragma unroll
  for (int reg = 0; reg < 4; reg++){
    float v = dacc[reg];
    v += __shfl_xor(v, 1);
    v += __shfl_xor(v, 2);
    v += __shfl_xor(v, 4);
    v += __shfl_xor(v, 8);
    if (col == 0) den[wv*16 + quad*4 + reg] = v;
  }

  __syncthreads();
  if (tid < 64){
    float step = s_cf[500];
    float alpha = num[tid] / fmaxf(den[tid] + rw*num[tid], 1e-8f);
    sa[tid] = step * alpha;
  }
  __syncthreads();

  // ---- update: f_out = f - step*alpha*fgrad (coalesced) ----
  float* oimg = f_out + (size_t)bb * CHW;
  for (int e = tid; e < 8192; e += 256){
    int x = e & 15, y = (e >> 4) & 3, c = e >> 6;
    size_t gi = (size_t)c * HW + (y0 + y) * WW + x0 + x;
    float v = fimg[gi] - sa[y*16 + x] * bf2f(fgs[(y*16 + x)*CP + c]);
    oimg[gi] = v;
  }
}

// ---------------------------------------------------------------------------
extern "C" void kernel_launch(void* const* d_in, const int* in_sizes, int n_in,
                              void* d_out, int out_size, void* d_ws, size_t ws_size,
                              hipStream_t stream) {
  const float* filter_map = (const float*)d_in[0];
  const float* ref        = (const float*)d_in[1];
  const float* label_w    = (const float*)d_in[2];
  const float* spatial_w  = (const float*)d_in[3];
  const float* mask_w     = (const float*)d_in[4];
  const float* lsl        = (const float*)d_in[5];
  const float* freg       = (const float*)d_in[6];

  float* coef = (float*)d_ws;      // coef tables (64 KB region reserved)
  float* fbuf = (float*)d_out;     // evolving filter lives in d_out (fp32)

  // bf16 pre-transposed ref copies in workspace (guarded by ws_size)
  short* refT = (short*)((char*)d_ws + 65536);
  short* refU = refT + (size_t)BB * CHW;
  size_t need = 65536 + 2 * (size_t)BB * CHW * sizeof(short);
  bool pre = (ws_size >= need);

  coef_kernel<<<dim3(1), dim3(128), 0, stream>>>(label_w, spatial_w, mask_w, lsl, freg, coef);
  if (pre)
    cvt_kernel<<<dim3(HH, BB), dim3(256), 0, stream>>>(ref, refT, refU);

  dim3 grid(8, 32, BB);   // 16-col x-tiles, 4-row y-bands, batch
  for (int it = 0; it < 3; it++){
    const float* fsrc = (it == 0) ? filter_map : (const float*)fbuf;
    if (pre) kF<1><<<grid, 256, 0, stream>>>(fsrc, ref, refT, refU, coef, fbuf);
    else     kF<0><<<grid, 256, 0, stream>>>(fsrc, ref, refT, refU, coef, fbuf);
  }
}

// Round 11
// 318.270 us; speedup vs baseline: 1.4678x; 1.4678x over previous
//
#include <hip/hip_runtime.h>

#define BB 4
#define CC 128
#define HH 128
#define WW 128
#define HW (HH*WW)
#define CHW (CC*HW)
#define ND 81
#define CP 136      // c-stride (shorts) for scr: 272 B rows -> 16B aligned, 2-way-free b128 reads
#define UPITCH 40   // u-stride (shorts) for cu: 80 B rows = 5x16B -> b128-aligned, 2-way-free
#define PP 40       // P tile u stride (shorts): 80 B rows -> pa b128 read 2-way

typedef short s8v __attribute__((ext_vector_type(8)));   // 8 bf16 MFMA A/B frag
typedef short s4v __attribute__((ext_vector_type(4)));
typedef float f4v __attribute__((ext_vector_type(4)));   // MFMA C/D frag

__device__ __forceinline__ short f2bf(float x){          // RNE float->bf16 bits
  unsigned u = __float_as_uint(x);
  unsigned r = (u + 0x7FFFu + ((u >> 16) & 1u)) >> 16;
  return (short)r;
}
__device__ __forceinline__ float bf2f(short s){
  return __uint_as_float(((unsigned)(unsigned short)s) << 16);
}

// ---------------------------------------------------------------------------
// coef: paired sign-case tables (bank-spread, one b64 gather per element):
//   coef[(d*3+case)*2+0] = g2 = ga^2, [..+1] = gt = ga*vp*t
//   ga = vp (s>0), vp*wm (s<0), vp*ah (s==0)  [a_lo+a_hi=1, a_hi-a_lo=wm]
// m = g2*s - gt exactly; den elem = g2*t*t.  [500]=step, [501]=reg_weight
// ---------------------------------------------------------------------------
__global__ void coef_kernel(const float* lw, const float* sw, const float* mw,
                            const float* lsl, const float* fr, float* coef){
  int d = threadIdx.x;
  if (d < ND){
    float dy = (float)(d / 9) - 4.0f;
    float dx = (float)(d % 9) - 4.0f;
    float dist = sqrtf(dy*dy + dx*dx) * 2.0f;
    float t = 0.f, v = 0.f, m = 0.f;
    for (int k = 0; k < 10; k++){
      float bd = dist - (float)k;
      float val = (k == 9) ? fminf(fmaxf(bd + 1.0f, 0.f), 1.f)
                           : fmaxf(1.0f - fabsf(bd), 0.f);
      t += val * lw[k]; v += val * sw[k]; m += val * mw[k];
    }
    float wm = 1.f / (1.f + expf(-m));
    float ah = (1.f + wm) * 0.5f;
    float gp = v, gn = v * wm, gz = v * ah;   // ga per sign case
    float vt = v * t;
    coef[(d*3+0)*2+0] = gp * gp;  coef[(d*3+0)*2+1] = gp * vt;
    coef[(d*3+1)*2+0] = gn * gn;  coef[(d*3+1)*2+1] = gn * vt;
    coef[(d*3+2)*2+0] = gz * gz;  coef[(d*3+2)*2+1] = gz * vt;
  }
  if (threadIdx.x == 0){
    coef[500] = expf(lsl[0]);
    float f = fr[0];
    coef[501] = fmaxf(f*f, 1e-10f) / (float)(CC*CC);
  }
}

// ---------------------------------------------------------------------------
// one-time convert: ref fp32 [b][c][h][w] ->
//   refU bf16 [b][h][c][w]  (u-contiguous, feeds cu staging)
//   refT bf16 [b][h][w][c]  (c-contiguous, feeds uc staging)
// ---------------------------------------------------------------------------
__global__ __launch_bounds__(256)
void cvt_kernel(const float* ref, short* refT, short* refU){
  __shared__ short T[128*130];
  int r = blockIdx.x, bb = blockIdx.y;
  int tid = threadIdx.x;
  const float* src = ref + (size_t)bb*CHW + (size_t)r*WW;
  short* uout = refU + (size_t)(bb*HH + r) * CC * WW;
  short* tout = refT + (size_t)(bb*HH + r) * WW * CC;
  #pragma unroll
  for (int k = 0; k < 16; k++){
    int q = tid + (k << 8);                 // 4096 float4 chunks
    int c = q >> 5, u0 = (q & 31) * 4;
    float4 v = *(const float4*)(src + (size_t)c*HW + u0);
    short h0 = f2bf(v.x), h1 = f2bf(v.y), h2 = f2bf(v.z), h3 = f2bf(v.w);
    s4v pk = {h0, h1, h2, h3};
    *(s4v*)&uout[(size_t)c*WW + u0] = pk;
    T[c*130 + u0 + 0] = h0; T[c*130 + u0 + 1] = h1;
    T[c*130 + u0 + 2] = h2; T[c*130 + u0 + 3] = h3;
  }
  __syncthreads();
  #pragma unroll
  for (int k = 0; k < 16; k++){
    int o = tid + (k << 8);
    int u = o >> 5, c0 = (o & 31) * 4;
    s4v pk = {T[(c0+0)*130 + u], T[(c0+1)*130 + u],
              T[(c0+2)*130 + u], T[(c0+3)*130 + u]};
    *(s4v*)&tout[(size_t)u*CC + c0] = pk;
  }
}

// ---------------------------------------------------------------------------
// kF round 11 = R8's 8-row/8-wave geometry (16 slides serve 8 rows, halving
// staging+barriers per output vs R7) with the LDS hog removed so TWO blocks
// fit per CU (R8: 47.1 KB -> 1 block -> 110 us at 21% occ).
//  * fgs (34.8 KB) deleted: fgrad bf16 lives in 16 packed regs (fgb, exact
//    same single f2bf(D + rw*fv) rounding)
//  * its consumers (ga_ frags, num, final update) run through a 2-round
//    scratch protocol overlaying the uc+cu region (17.4 KB, dead between
//    phases): waves 4r..4r+3 write rows -> barrier -> read; update repeats
//    the rounds with a coalesced 4-row pass.
// LDS 32.8 KB -> 2 blocks/CU = 16 waves/CU at half the slides of R7.
// launch_bounds(512,4): VGPR cap 128 >= ~100 live (R5's failure was cap 85).
// ---------------------------------------------------------------------------
#define L_UC   0        // 8704 (slides; scr overlays uc+cu between phases)
#define L_CU   8704     // 10240
#define L_PM   18944    // 10240 (8 wv x 16 x x PP)
#define L_CF   29184    // 512 floats = 2048
#define L_DEN  31232
#define L_NUM  31744
#define L_SA   32256
#define L_SZ   32768

template<int PRE>
__global__ __launch_bounds__(512, 4)
void kF(const float* f_in, const float* ref, const short* refT, const short* refU,
        const float* coef, float* f_out){
  __shared__ char smem[L_SZ];
  short* uc  = (short*)(smem + L_UC);    // [32 u][CP c]   (corr B-operand)
  short* cu  = (short*)(smem + L_CU);    // [128 c][UPITCH u] (corr_t B-operand)
  short* scr = (short*)(smem + L_UC);    // [4 slot][16 x][CP c] fgrad scratch
  short* Pm  = (short*)(smem + L_PM);    // [8 wv][16 x][PP u]
  float* s_cf = (float*)(smem + L_CF);   // paired table + step/rw
  float* den = (float*)(smem + L_DEN);
  float* num = (float*)(smem + L_NUM);
  float* sa  = (float*)(smem + L_SA);

  int tid = threadIdx.x;
  int lane = tid & 63, wv = tid >> 6;          // 8 waves
  int quad = lane >> 4, col = lane & 15;

  // XCD-chunked bijective swizzle (512 blocks, 8 XCDs, chunk 64)
  int hwid = blockIdx.x + (blockIdx.y << 3) + (blockIdx.z << 7);
  int virt = ((hwid & 7) << 6) + (hwid >> 3);
  int bb = virt >> 7, y0 = ((virt >> 3) & 15) * 8, x0 = (virt & 7) * 16;

  int ub = x0 - 8;

  const float* fimg = f_in + (size_t)bb * CHW;
  const float* rimg = ref  + (size_t)bb * CHW;

  // ---- prefetch registers (PRE=1: bf16 chunks; PRE=0: raw fp32) ----
  s8v pT0, pU0;
  float4 pF0, pF1;

  auto loadT = [&](int r){
    if constexpr (PRE){
      const short* tb = refT + (size_t)(bb*HH + r) * WW * CC;
      int ua = ub + (tid >> 4);
      pT0 = (ua >= 0 && ua < WW)
            ? *(const s8v*)(tb + (size_t)ua*CC + ((tid & 15) << 3)) : (s8v)(short)0;
    } else {
      const float* rb = rimg + (size_t)r * WW;
      float4 z; z.x = z.y = z.z = z.w = 0.f;
      { int e = tid;       int ua = ub + (e & 7)*4;
        pF0 = (ua >= 0 && ua + 4 <= WW) ? *(const float4*)(rb + (size_t)(e >> 3)*HW + ua) : z; }
      { int e = tid + 512; int ua = ub + (e & 7)*4;
        pF1 = (ua >= 0 && ua + 4 <= WW) ? *(const float4*)(rb + (size_t)(e >> 3)*HW + ua) : z; }
    }
  };
  auto loadU = [&](int r){
    if constexpr (PRE){
      const short* ubp = refU + (size_t)(bb*HH + r) * CC * WW;
      int ua = ub + ((tid & 3) << 3);
      pU0 = (ua >= 0 && ua + 8 <= WW)
            ? *(const s8v*)(ubp + (size_t)(tid >> 2)*WW + ua) : (s8v)(short)0;
    }
  };
  auto writeRowA = [&](){
    if constexpr (PRE){
      *(s8v*)&uc[(tid >> 4)*CP + ((tid & 15) << 3)] = pT0;
      *(s8v*)&cu[(tid >> 2)*UPITCH + ((tid & 3) << 3)] = pU0;
    } else {
      float4 vv[2] = {pF0, pF1};
      #pragma unroll
      for (int k = 0; k < 2; k++){
        int e4 = tid + (k << 9);
        int u4 = (e4 & 7) * 4, c = e4 >> 3;
        short h0 = f2bf(vv[k].x), h1 = f2bf(vv[k].y),
              h2 = f2bf(vv[k].z), h3 = f2bf(vv[k].w);
        uc[(u4+0)*CP + c] = h0; uc[(u4+1)*CP + c] = h1;
        uc[(u4+2)*CP + c] = h2; uc[(u4+3)*CP + c] = h3;
        s4v pk = {h0, h1, h2, h3};
        *(s4v*)&cu[c*UPITCH + u4] = pk;
      }
    }
  };
  auto writeRowB = [&](){
    if constexpr (PRE){
      *(s8v*)&uc[(tid >> 4)*CP + ((tid & 15) << 3)] = pT0;
    } else {
      float4 vv[2] = {pF0, pF1};
      #pragma unroll
      for (int k = 0; k < 2; k++){
        int e4 = tid + (k << 9);
        int u4 = (e4 & 7) * 4, c = e4 >> 3;
        uc[(u4+0)*CP + c] = f2bf(vv[k].x); uc[(u4+1)*CP + c] = f2bf(vv[k].y);
        uc[(u4+2)*CP + c] = f2bf(vv[k].z); uc[(u4+3)*CP + c] = f2bf(vv[k].w);
      }
    }
  };

  // prologue: loads for rr=0 (row y0-4), in flight under coef copy + A-frags
  if (y0 - 4 >= 0){ loadT(y0 - 4); loadU(y0 - 4); }

  if (tid < 512) s_cf[tid] = coef[tid];

  // ---- A-frags (f at row y0+wv, hi/lo split) straight from global ----
  int fy = y0 + wv;
  s8v a_hi[4], a_lo[4];
  #pragma unroll
  for (int kc = 0; kc < 4; kc++){
    short th[8], tl[8];
    #pragma unroll
    for (int j = 0; j < 8; j++){
      int c = kc*32 + quad*8 + j;
      float v = fimg[(size_t)c * HW + fy * WW + x0 + col];
      short h = f2bf(v);
      th[j] = h; tl[j] = f2bf(v - bf2f(h));
    }
    a_hi[kc] = *(const s8v*)th;
    a_lo[kc] = *(const s8v*)tl;
  }

  f4v D[8];
  #pragma unroll
  for (int i = 0; i < 8; i++) D[i] = (f4v)0.f;

  // sign FIFO: 9 x 16-bit packs in 3 u64 (push A, pop B, same order)
  unsigned long long f0 = 0ull, f1 = 0ull, f2 = 0ull;

  // =================== phase A: corr1 -> P -> corr_t ===================
  for (int rr = 0; rr < 16; rr++){
    int r = y0 + rr - 4;
    bool rv = (r >= 0) && (r < HH);
    __syncthreads();
    if (rv) writeRowA();
    __syncthreads();
    // next row's loads issued NOW: the vmcnt(0)-drain at the next barrier
    // is covered by the compute below
    if (rr < 15){
      int rn = r + 1;
      if (rn >= 0 && rn < HH){ loadT(rn); loadU(rn); }
    }
    int dy = rr - wv;
    if (dy >= 0 && dy <= 8){
      unsigned pack = 0u;
      if (rv){
        // corr1: C[x,u] = sum_c (f_hi+f_lo)[x,c] * ref[c,u]
        f4v C0 = (f4v)0.f, C1 = (f4v)0.f;
        #pragma unroll
        for (int kc = 0; kc < 4; kc++){
          s8v b0 = *(const s8v*)&uc[col*CP      + kc*32 + quad*8];
          s8v b1 = *(const s8v*)&uc[(16+col)*CP + kc*32 + quad*8];
          C0 = __builtin_amdgcn_mfma_f32_16x16x32_bf16(a_hi[kc], b0, C0, 0,0,0);
          C0 = __builtin_amdgcn_mfma_f32_16x16x32_bf16(a_lo[kc], b0, C0, 0,0,0);
          C1 = __builtin_amdgcn_mfma_f32_16x16x32_bf16(a_hi[kc], b1, C1, 0,0,0);
          C1 = __builtin_amdgcn_mfma_f32_16x16x32_bf16(a_lo[kc], b1, C1, 0,0,0);
        }
        // scores -> sign pack (regs) + mapped -> P[x,u]
        #pragma unroll
        for (int nt = 0; nt < 2; nt++){
          f4v Cv = nt ? C1 : C0;
          #pragma unroll
          for (int reg = 0; reg < 4; reg++){
            int x  = quad*4 + reg;            // C/D row = (lane>>4)*4 + reg
            int up = nt*16 + col;             // C/D col = lane&15 (+tile)
            int dxm = up - x - 4;
            float m = 0.f;
            if ((unsigned)dxm <= 8u){
              float s = Cv[reg];
              int d = dy*9 + dxm;
              unsigned pos = (s > 0.f) ? 1u : 0u;
              unsigned neg = (s < 0.f) ? 1u : 0u;
              int cse = pos ? 0 : (neg ? 1 : 2);
              float2 gg = *(const float2*)&s_cf[(d*3 + cse)*2];
              m = fmaf(gg.x, s, -gg.y);
              pack |= (pos | (neg << 1)) << ((nt*4 + reg) * 2);
            }
            Pm[(wv*16 + x)*PP + up] = f2bf(m);
          }
        }
        // wave-local LDS handoff (keep global prefetch in flight)
        asm volatile("s_waitcnt lgkmcnt(0)" ::: "memory");
        __builtin_amdgcn_sched_barrier(0);
        // corr_t: D[x,c] += sum_u P[x,u] * ref[u,c]
        s8v pa = *(const s8v*)&Pm[(wv*16 + col)*PP + quad*8];
        #pragma unroll
        for (int ct = 0; ct < 8; ct++){
          s8v bc = *(const s8v*)&cu[(ct*16 + col)*UPITCH + quad*8];
          D[ct] = __builtin_amdgcn_mfma_f32_16x16x32_bf16(pa, bc, D[ct], 0,0,0);
        }
      }
      // FIFO push (always when dy in window, so A/B stay aligned)
      f0 = (f0 >> 16) | (f1 << 48);
      f1 = (f1 >> 16) | (f2 << 48);
      f2 = (f2 >> 16) | ((unsigned long long)pack << 48);
    }
  }

  // phase-B prologue loads fly under the epilogue work
  if (y0 - 4 >= 0) loadT(y0 - 4);

  // ---- epilogue-1: fgrad bf16 packed in regs (same single rounding) ----
  float rw = s_cf[501];
  s8v fgb[4];
  #pragma unroll
  for (int ct = 0; ct < 8; ct++){
    #pragma unroll
    for (int reg = 0; reg < 4; reg++){
      int x = quad*4 + reg, c = ct*16 + col;
      float fv = fimg[(size_t)c * HW + fy * WW + x0 + x];
      int idx = ct*4 + reg;
      fgb[idx >> 3][idx & 7] = f2bf(D[ct][reg] + rw * fv);
    }
  }

  // ---- 2-round scratch: waves 4r..4r+3 publish rows -> ga_ frags + num ----
  s8v ga_[4];
  #pragma unroll
  for (int rnd = 0; rnd < 2; rnd++){
    __syncthreads();
    if ((wv >> 2) == rnd){
      int slot = wv & 3;
      #pragma unroll
      for (int ct = 0; ct < 8; ct++){
        #pragma unroll
        for (int reg = 0; reg < 4; reg++){
          int x = quad*4 + reg, c = ct*16 + col;
          int idx = ct*4 + reg;
          scr[(slot*16 + x)*CP + c] = fgb[idx >> 3][idx & 7];
        }
      }
    }
    __syncthreads();
    if ((wv >> 2) == rnd){
      int slot = wv & 3;
      #pragma unroll
      for (int kc = 0; kc < 4; kc++)
        ga_[kc] = *(const s8v*)&scr[(slot*16 + col)*CP + kc*32 + quad*8];
      // num: lane covers (x=lane&15, chunk=lane>>4), 32 c's each
      int xx = lane & 15, ch = lane >> 4;
      float s = 0.f;
      #pragma unroll
      for (int j = 0; j < 4; j++){
        s8v v = *(const s8v*)&scr[(slot*16 + xx)*CP + ch*32 + j*8];
        #pragma unroll
        for (int jj = 0; jj < 8; jj++){ float f = bf2f(v[jj]); s += f*f; }
      }
      s += __shfl_xor(s, 16);
      s += __shfl_xor(s, 32);
      if (ch == 0) num[wv*16 + xx] = s;
    }
  }

  // =================== phase B: corr(fgrad) -> den ===================
  float dacc[4] = {0.f, 0.f, 0.f, 0.f};    // per-thread den partials (by reg)

  for (int rr = 0; rr < 16; rr++){
    int r = y0 + rr - 4;
    bool rv = (r >= 0) && (r < HH);
    __syncthreads();
    if (rv) writeRowB();
    __syncthreads();
    if (rr < 15){
      int rn = r + 1;
      if (rn >= 0 && rn < HH) loadT(rn);
    }
    int dy = rr - wv;
    if (dy >= 0 && dy <= 8){
      // FIFO pop (mirrors phase-A push order)
      unsigned pack = (unsigned)(f0 >> 48) & 0xFFFFu;
      f0 = (f0 >> 16) | (f1 << 48);
      f1 = (f1 >> 16) | (f2 << 48);
      f2 >>= 16;
      if (rv){
        f4v C0 = (f4v)0.f, C1 = (f4v)0.f;
        #pragma unroll
        for (int kc = 0; kc < 4; kc++){
          s8v b0 = *(const s8v*)&uc[col*CP      + kc*32 + quad*8];
          s8v b1 = *(const s8v*)&uc[(16+col)*CP + kc*32 + quad*8];
          C0 = __builtin_amdgcn_mfma_f32_16x16x32_bf16(ga_[kc], b0, C0, 0,0,0);
          C1 = __builtin_amdgcn_mfma_f32_16x16x32_bf16(ga_[kc], b1, C1, 0,0,0);
        }
        #pragma unroll
        for (int nt = 0; nt < 2; nt++){
          f4v Cv = nt ? C1 : C0;
          #pragma unroll
          for (int reg = 0; reg < 4; reg++){
            int x  = quad*4 + reg;
            int up = nt*16 + col;
            int dxm = up - x - 4;
            if ((unsigned)dxm <= 8u){
              int d = dy*9 + dxm;
              unsigned b2 = pack >> ((nt*4 + reg) * 2);
              int cse = (b2 & 1u) ? 0 : ((b2 & 2u) ? 1 : 2);
              float g2 = s_cf[(d*3 + cse)*2];
              float t  = Cv[reg];
              dacc[reg] = fmaf(g2 * t, t, dacc[reg]);
            }
          }
        }
      }
    }
  }

  // den: reduce partials across the 16 col-lanes of each quad (no atomics)
  #pragma unroll
  for (int reg = 0; reg < 4; reg++){
    float v = dacc[reg];
    v += __shfl_xor(v, 1);
    v += __shfl_xor(v, 2);
    v += __shfl_xor(v, 4);
    v += __shfl_xor(v, 8);
    if (col == 0) den[wv*16 + quad*4 + reg] = v;
  }

  __syncthreads();
  if (tid < 128){
    float step = s_cf[500];
    float alpha = num[tid] / fmaxf(den[tid] + rw*num[tid], 1e-8f);
    sa[tid] = step * alpha;
  }

  // ---- update in 2 rounds through scratch (coalesced 4-row passes) ----
  float* oimg = f_out + (size_t)bb * CHW;
  #pragma unroll
  for (int rnd = 0; rnd < 2; rnd++){
    __syncthreads();   // sa ready (rnd 0) / prior round's reads done (rnd 1)
    if ((wv >> 2) == rnd){
      int slot = wv & 3;
      #pragma unroll
      for (int ct = 0; ct < 8; ct++){
        #pragma unroll
        for (int reg = 0; reg < 4; reg++){
          int x = quad*4 + reg, c = ct*16 + col;
          int idx = ct*4 + reg;
          scr[(slot*16 + x)*CP + c] = fgb[idx >> 3][idx & 7];
        }
      }
    }
    __syncthreads();
    for (int e = tid; e < 8192; e += 512){
      int x = e & 15, yl = (e >> 4) & 3, c = e >> 6;
      size_t gi = (size_t)c * HW + (y0 + rnd*4 + yl) * WW + x0 + x;
      float v = fimg[gi] - sa[(rnd*4 + yl)*16 + x] * bf2f(scr[(yl*16 + x)*CP + c]);
      oimg[gi] = v;
    }
  }
}

// ---------------------------------------------------------------------------
extern "C" void kernel_launch(void* const* d_in, const int* in_sizes, int n_in,
                              void* d_out, int out_size, void* d_ws, size_t ws_size,
                              hipStream_t stream) {
  const float* filter_map = (const float*)d_in[0];
  const float* ref        = (const float*)d_in[1];
  const float* label_w    = (const float*)d_in[2];
  const float* spatial_w  = (const float*)d_in[3];
  const float* mask_w     = (const float*)d_in[4];
  const float* lsl        = (const float*)d_in[5];
  const float* freg       = (const float*)d_in[6];

  float* coef = (float*)d_ws;      // coef tables (64 KB region reserved)
  float* fbuf = (float*)d_out;     // evolving filter lives in d_out (fp32)

  // bf16 pre-transposed ref copies in workspace (guarded by ws_size)
  short* refT = (short*)((char*)d_ws + 65536);
  short* refU = refT + (size_t)BB * CHW;
  size_t need = 65536 + 2 * (size_t)BB * CHW * sizeof(short);
  bool pre = (ws_size >= need);

  coef_kernel<<<dim3(1), dim3(128), 0, stream>>>(label_w, spatial_w, mask_w, lsl, freg, coef);
  if (pre)
    cvt_kernel<<<dim3(HH, BB), dim3(256), 0, stream>>>(ref, refT, refU);

  dim3 grid(8, 16, BB);   // 16-col x-tiles, 8-row y-bands, batch
  for (int it = 0; it < 3; it++){
    const float* fsrc = (it == 0) ? filter_map : (const float*)fbuf;
    if (pre) kF<1><<<grid, 512, 0, stream>>>(fsrc, ref, refT, refU, coef, fbuf);
    else     kF<0><<<grid, 512, 0, stream>>>(fsrc, ref, refT, refU, coef, fbuf);
  }
}